// Round 1
// baseline (2285.236 us; speedup 1.0000x reference)
//
#include <hip/hip_runtime.h>
#include <math.h>

#define HH 512
#define WW 512
#define HWSZ (HH * WW)          // 262144 = 2^18
#define NB 4
#define NPIX (NB * HWSZ)        // 1048576 = 2^20
#define TMAX 16
#define CCL_ITERS 128

static constexpr double dSP0 = 0.6931471805599453;   // softplus(0)
static constexpr double dSP1 = 1.3132616875182228;   // softplus(1)
static constexpr double dS1  = 0.7310585786300049;   // sigmoid(1)

struct Scalars {
  double bce_sum;
  double sum_p;
  double sum_inter;
  double sum_t;
  double acc;
  int cnt_t[TMAX + 1];
  int n_pred;
  int matched;
  int un_tgt;
  unsigned long long best;   // (loss_bits << 32) | comp_index, min-reduced
};

__global__ void k_init_scalars(Scalars* sc) {
  sc->bce_sum = 0.0; sc->sum_p = 0.0; sc->sum_inter = 0.0; sc->sum_t = 0.0;
  sc->acc = 0.0;
  for (int i = 0; i <= TMAX; ++i) sc->cnt_t[i] = 0;
  sc->n_pred = 0; sc->matched = 0; sc->un_tgt = 0;
  sc->best = ~0ULL;
}

// One pass: fg mask + init labels + base-loss partial sums + target histogram.
__global__ __launch_bounds__(256) void k_init(const float* __restrict__ pred,
                                              const int* __restrict__ tgt,
                                              int* __restrict__ lab,
                                              Scalars* sc) {
  int i = blockIdx.x * 256 + threadIdx.x;
  int b = i >> 18;            // / HWSZ
  int hw = i & (HWSZ - 1);
  float p0 = pred[(b * 2 + 0) * HWSZ + hw];
  float p1 = pred[(b * 2 + 1) * HWSZ + hw];
  int tv = tgt[i];
  bool fg = p1 > p0;          // argmax over C=2, tie -> channel 0
  float logit = fg ? p1 : 0.0f;
  float tb = (tv > 0) ? 1.0f : 0.0f;
  // stable softplus
  float sp = fmaxf(logit, 0.0f) + log1pf(expf(-fabsf(logit)));
  float bce = sp - logit * tb;
  float pr = 1.0f / (1.0f + expf(-logit));
  lab[i] = fg ? (i + 1) : 0;

  __shared__ int hist[TMAX + 1];
  __shared__ float red[4][4];
  if (threadIdx.x <= TMAX) hist[threadIdx.x] = 0;
  __syncthreads();
  int tvc = tv < 0 ? 0 : (tv > TMAX ? TMAX : tv);
  atomicAdd(&hist[tvc], 1);

  float v0 = bce, v1 = pr, v2 = pr * tb, v3 = tb;
  for (int o = 32; o > 0; o >>= 1) {
    v0 += __shfl_down(v0, o);
    v1 += __shfl_down(v1, o);
    v2 += __shfl_down(v2, o);
    v3 += __shfl_down(v3, o);
  }
  int lane = threadIdx.x & 63, wid = threadIdx.x >> 6;
  if (lane == 0) { red[wid][0] = v0; red[wid][1] = v1; red[wid][2] = v2; red[wid][3] = v3; }
  __syncthreads();
  if (threadIdx.x <= TMAX) atomicAdd(&sc->cnt_t[threadIdx.x], hist[threadIdx.x]);
  if (threadIdx.x == 0) {
    double s0 = 0, s1 = 0, s2 = 0, s3 = 0;
    for (int w = 0; w < 4; ++w) { s0 += red[w][0]; s1 += red[w][1]; s2 += red[w][2]; s3 += red[w][3]; }
    atomicAdd(&sc->bce_sum, s0);
    atomicAdd(&sc->sum_p, s1);
    atomicAdd(&sc->sum_inter, s2);
    atomicAdd(&sc->sum_t, s3);
  }
}

// One Jacobi max-propagation step (4-connected, per-batch image).
__global__ __launch_bounds__(256) void k_prop(const int* __restrict__ src,
                                              int* __restrict__ dst) {
  int i = blockIdx.x * 256 + threadIdx.x;
  int v = src[i];
  if (v != 0) {
    int hw = i & (HWSZ - 1);
    int h = hw >> 9;
    int w = hw & (WW - 1);
    int m = v;
    if (h > 0)      m = max(m, src[i - WW]);
    if (h < HH - 1) m = max(m, src[i + WW]);
    if (w > 0)      m = max(m, src[i - 1]);
    if (w < WW - 1) m = max(m, src[i + 1]);
    dst[i] = m;
  } else {
    dst[i] = 0;
  }
}

__global__ __launch_bounds__(256) void k_count(const int* __restrict__ lab,
                                               int* __restrict__ cnt) {
  int i = blockIdx.x * 256 + threadIdx.x;
  int v = lab[i];
  if (v > 0) atomicAdd(&cnt[v - 1], 1);
}

__global__ __launch_bounds__(256) void k_npred(const int* __restrict__ cnt, Scalars* sc) {
  int p = blockIdx.x * 256 + threadIdx.x;
  int v = (cnt[p] > 0) ? 1 : 0;
  for (int o = 32; o > 0; o >>= 1) v += __shfl_down(v, o);
  __shared__ int red[4];
  int lane = threadIdx.x & 63, wid = threadIdx.x >> 6;
  if (lane == 0) red[wid] = v;
  __syncthreads();
  if (threadIdx.x == 0) atomicAdd(&sc->n_pred, red[0] + red[1] + red[2] + red[3]);
}

__global__ __launch_bounds__(256) void k_inter(const int* __restrict__ lab,
                                               const int* __restrict__ tgt,
                                               int* __restrict__ inter, int t) {
  int i = blockIdx.x * 256 + threadIdx.x;
  int v = lab[i];
  if (v > 0 && tgt[i] == t) atomicAdd(&inter[v - 1], 1);
}

__global__ __launch_bounds__(256) void k_argmin(const int* __restrict__ cnt,
                                                int* __restrict__ inter,
                                                Scalars* sc, int t) {
  int p = blockIdx.x * 256 + threadIdx.x;
  int c = cnt[p];
  int iv = inter[p];
  inter[p] = 0;   // reset for next t
  unsigned long long key = ~0ULL;
  if (c > 0) {    // available: nonzero size and not used (used => negated)
    const float Nf = (float)NPIX;
    float ct = (float)sc->cnt_t[t];
    float cp = (float)c;
    float it = (float)iv;
    float bce = (Nf * (float)dSP0 + cp * (float)(dSP1 - dSP0) - it) / Nf;
    float sum_pt = 0.5f * ct + (float)(dS1 - 0.5) * it;
    float sum_pp = 0.5f * Nf + (float)(dS1 - 0.5) * cp;
    float dice = 1.0f - (2.0f * sum_pt + 1.0f) / (sum_pp + ct + 1.0f);
    float loss = bce + dice;  // always > 0
    key = ((unsigned long long)__float_as_uint(loss) << 32) | (unsigned int)p;
  }
  for (int o = 32; o > 0; o >>= 1) {
    unsigned long long other = __shfl_down(key, o);
    key = (other < key) ? other : key;
  }
  __shared__ unsigned long long wmin[4];
  int lane = threadIdx.x & 63, wid = threadIdx.x >> 6;
  if (lane == 0) wmin[wid] = key;
  __syncthreads();
  if (threadIdx.x == 0) {
    unsigned long long k2 = wmin[0];
    for (int w = 1; w < 4; ++w) k2 = (wmin[w] < k2) ? wmin[w] : k2;
    if (k2 != ~0ULL) atomicMin(&sc->best, k2);
  }
}

__global__ void k_stepfin(Scalars* sc, int* __restrict__ cnt, int t) {
  unsigned long long b = sc->best;
  int ct = sc->cnt_t[t];
  bool present = ct > 0;
  bool any = (b != ~0ULL);
  if (present && any) {
    float loss = __uint_as_float((unsigned int)(b >> 32));
    sc->acc += (double)loss;
    int idx = (int)(b & 0xFFFFFFFFu);
    cnt[idx] = -cnt[idx];     // mark used
    sc->matched += 1;
  } else if (present) {
    sc->un_tgt += 1;
  }
  sc->best = ~0ULL;
}

__global__ void k_final(const Scalars* sc, float* out) {
  double Nd = (double)NPIX;
  double res = sc->bce_sum / Nd
             + 1.0 - (2.0 * sc->sum_inter + 1.0) / (sc->sum_p + sc->sum_t + 1.0);
  double total = res + sc->acc
               + (double)(sc->n_pred - sc->matched) + (double)sc->un_tgt;
  out[0] = (float)total;
}

extern "C" void kernel_launch(void* const* d_in, const int* in_sizes, int n_in,
                              void* d_out, int out_size, void* d_ws, size_t ws_size,
                              hipStream_t stream) {
  (void)in_sizes; (void)n_in; (void)out_size; (void)ws_size;
  const float* pred = (const float*)d_in[0];
  const int* tgt = (const int*)d_in[1];
  float* out = (float*)d_out;

  int* lab_a = (int*)d_ws;
  int* lab_b = lab_a + NPIX;
  int* cnt   = lab_b + NPIX;
  Scalars* sc = (Scalars*)(cnt + NPIX);

  const int grid = NPIX / 256;

  hipMemsetAsync(cnt, 0, NPIX * sizeof(int), stream);
  k_init_scalars<<<1, 1, 0, stream>>>(sc);
  k_init<<<grid, 256, 0, stream>>>(pred, tgt, lab_a, sc);

  for (int k = 0; k < CCL_ITERS; k += 2) {
    k_prop<<<grid, 256, 0, stream>>>(lab_a, lab_b);
    k_prop<<<grid, 256, 0, stream>>>(lab_b, lab_a);
  }

  k_count<<<grid, 256, 0, stream>>>(lab_a, cnt);
  k_npred<<<grid, 256, 0, stream>>>(cnt, sc);

  hipMemsetAsync(lab_b, 0, NPIX * sizeof(int), stream);  // inter buffer
  for (int t = 1; t <= TMAX; ++t) {
    k_inter<<<grid, 256, 0, stream>>>(lab_a, tgt, lab_b, t);
    k_argmin<<<grid, 256, 0, stream>>>(cnt, lab_b, sc, t);
    k_stepfin<<<1, 1, 0, stream>>>(sc, cnt, t);
  }

  k_final<<<1, 1, 0, stream>>>(sc, out);
}

// Round 2
// 905.706 us; speedup vs baseline: 2.5232x; 2.5232x over previous
//
#include <hip/hip_runtime.h>
#include <math.h>

#define HH 512
#define WW 512
#define HWSZ (HH * WW)          // 262144
#define NB 4
#define NPIX (NB * HWSZ)        // 1048576
#define TMAX 16
#define CCL_ITERS 128

// tiled propagation: interior TI x TI, halo RR, loaded TL x TL
#define TI 56
#define RR 16
#define TL 88                   // TI + 2*RR ; 2*88*88*4 = 61952 B LDS
#define NTY 10                  // ceil(512/56)
#define PROP_BLOCKS (NB * NTY * NTY)   // 400
#define PROP_THREADS 512

#define CAP 131072              // component capacity for dense arrays
#define INIT_BLOCKS 1024        // NPIX/4/256
#define NPART 24                // padded partials row (21 used)

struct Scalars {
  double sums[4];               // bce, sum_p, sum_pt, sum_t
  double acc;
  int cnt_t[TMAX + 1];
  int n_comp;
  int matched;
  int un_tgt;
  int arrive;
  unsigned long long best;      // (loss_bits<<32)|root, min-reduced
};

__device__ inline float pair_loss(float cp, float it, float ctf) {
  const float Nf = (float)NPIX;
  float bce = (Nf * 0.69314718f + cp * 0.62011451f - it) / Nf;  // SP0, SP1-SP0
  float sum_pt = 0.5f * ctf + 0.23105858f * it;                 // S1-0.5
  float sum_p = 0.5f * Nf + 0.23105858f * cp;
  float dice = 1.0f - (2.0f * sum_pt + 1.0f) / (sum_p + ctf + 1.0f);
  return bce + dice;   // always > 0 (bce >= 0.31, dice >= -0.19)
}

// ---- init: fg mask, labels, base-loss partial sums, target histogram ----
__global__ __launch_bounds__(256) void k_init(const float* __restrict__ pred,
                                              const int* __restrict__ tgt,
                                              int* __restrict__ lab,
                                              double* __restrict__ part) {
  __shared__ int hist[TMAX + 1];
  __shared__ double red[4][4];
  int tid = threadIdx.x;
  if (tid <= TMAX) hist[tid] = 0;
  __syncthreads();

  int g = blockIdx.x * 256 + tid;
  int i = g << 2;
  int b = i >> 18;
  int hw = i & (HWSZ - 1);
  const float* pb = pred + ((size_t)(b << 1)) * HWSZ;
  float4 p0 = *(const float4*)(pb + hw);
  float4 p1 = *(const float4*)(pb + HWSZ + hw);
  int4 tv = *(const int4*)(tgt + i);
  int4 lv;
  float s0 = 0.f, s1 = 0.f, s2 = 0.f, s3 = 0.f;

#define ELEM(P0, P1, TV, IDX, LOUT)                              \
  {                                                              \
    bool fg = (P1) > (P0);                                       \
    float logit = fg ? (P1) : 0.0f;                              \
    float tb = ((TV) > 0) ? 1.0f : 0.0f;                         \
    float sp = fmaxf(logit, 0.0f) + log1pf(expf(-fabsf(logit))); \
    s0 += sp - logit * tb;                                       \
    float pr = 1.0f / (1.0f + expf(-logit));                     \
    s1 += pr; s2 += pr * tb; s3 += tb;                           \
    atomicAdd(&hist[TV], 1);                                     \
    LOUT = fg ? ((IDX) + 1) : 0;                                 \
  }
  ELEM(p0.x, p1.x, tv.x, i + 0, lv.x)
  ELEM(p0.y, p1.y, tv.y, i + 1, lv.y)
  ELEM(p0.z, p1.z, tv.z, i + 2, lv.z)
  ELEM(p0.w, p1.w, tv.w, i + 3, lv.w)
#undef ELEM
  *(int4*)(lab + i) = lv;

  for (int o = 32; o > 0; o >>= 1) {
    s0 += __shfl_down(s0, o);
    s1 += __shfl_down(s1, o);
    s2 += __shfl_down(s2, o);
    s3 += __shfl_down(s3, o);
  }
  int lane = tid & 63, wid = tid >> 6;
  if (!lane) { red[wid][0] = s0; red[wid][1] = s1; red[wid][2] = s2; red[wid][3] = s3; }
  __syncthreads();
  double* row = part + (size_t)blockIdx.x * NPART;
  if (tid <= TMAX) row[4 + tid] = (double)hist[tid];
  if (!tid) {
    row[0] = red[0][0] + red[1][0] + red[2][0] + red[3][0];
    row[1] = red[0][1] + red[1][1] + red[2][1] + red[3][1];
    row[2] = red[0][2] + red[1][2] + red[2][2] + red[3][2];
    row[3] = red[0][3] + red[1][3] + red[2][3] + red[3][3];
  }
}

__global__ __launch_bounds__(256) void k_reduce(const double* __restrict__ part,
                                                Scalars* sc) {
  double v[21];
#pragma unroll
  for (int j = 0; j < 21; ++j) v[j] = 0.0;
  for (int r = threadIdx.x; r < INIT_BLOCKS; r += 256) {
    const double* row = part + (size_t)r * NPART;
#pragma unroll
    for (int j = 0; j < 21; ++j) v[j] += row[j];
  }
#pragma unroll
  for (int o = 32; o > 0; o >>= 1) {
#pragma unroll
    for (int j = 0; j < 21; ++j) v[j] += __shfl_down(v[j], o);
  }
  __shared__ double red[4][21];
  int lane = threadIdx.x & 63, wid = threadIdx.x >> 6;
  if (!lane) {
#pragma unroll
    for (int j = 0; j < 21; ++j) red[wid][j] = v[j];
  }
  __syncthreads();
  if (!threadIdx.x) {
#pragma unroll
    for (int j = 0; j < 21; ++j) v[j] = red[0][j] + red[1][j] + red[2][j] + red[3][j];
    sc->sums[0] = v[0]; sc->sums[1] = v[1]; sc->sums[2] = v[2]; sc->sums[3] = v[3];
    for (int j = 0; j <= TMAX; ++j) sc->cnt_t[j] = (int)(v[4 + j] + 0.5);
    sc->acc = 0.0;
    sc->n_comp = 0; sc->matched = 0; sc->un_tgt = 0; sc->arrive = 0;
    sc->best = ~0ULL;
  }
}

// ---- 16 exact Jacobi max-propagation steps per launch, LDS tiled ----
__global__ __launch_bounds__(PROP_THREADS) void k_prop_tile(const int* __restrict__ src,
                                                            int* __restrict__ dst) {
  __shared__ int s0[TL * TL];
  __shared__ int s1[TL * TL];
  int bid = blockIdx.x;
  int b = bid / (NTY * NTY);
  int rem = bid - b * (NTY * NTY);
  int ty = rem / NTY;
  int tx = rem - ty * NTY;
  int oh = ty * TI - RR;
  int ow = tx * TI - RR;
  const int* simg = src + (size_t)b * HWSZ;

  for (int c = threadIdx.x; c < TL * TL; c += PROP_THREADS) {
    int r = c / TL, q = c - r * TL;
    int h = oh + r, w = ow + q;
    int v = 0;
    if ((unsigned)h < (unsigned)HH && (unsigned)w < (unsigned)WW) v = simg[(h << 9) + w];
    s0[c] = v;
    s1[c] = 0;    // bg cells stay 0 in both buffers forever
  }
  __syncthreads();

  int* cur = s0;
  int* nxt = s1;
  for (int it = 0; it < RR; ++it) {
    for (int c = threadIdx.x; c < TL * TL; c += PROP_THREADS) {
      int v = cur[c];
      if (v != 0) {
        int r = c / TL;
        int q = c - r * TL;
        int up = (r > 0)      ? cur[c - TL] : 0;
        int dn = (r < TL - 1) ? cur[c + TL] : 0;
        int lf = (q > 0)      ? cur[c - 1]  : 0;
        int rt = (q < TL - 1) ? cur[c + 1]  : 0;
        nxt[c] = max(max(v, max(up, dn)), max(lf, rt));
      }
    }
    __syncthreads();
    int* tmp = cur; cur = nxt; nxt = tmp;
  }

  int* dimg = dst + (size_t)b * HWSZ;
  for (int c = threadIdx.x; c < TI * TI; c += PROP_THREADS) {
    int r = c / TI, q = c - r * TI;
    int h = oh + RR + r, w = ow + RR + q;
    if (h < HH && w < WW) dimg[(h << 9) + w] = cur[(r + RR) * TL + (q + RR)];
  }
}

__global__ __launch_bounds__(256) void k_count(const int* __restrict__ lab,
                                               int* __restrict__ cnt) {
  int g = blockIdx.x * 256 + threadIdx.x;
  int4 v = *(const int4*)(lab + ((size_t)g << 2));
  if (v.x) atomicAdd(&cnt[v.x - 1], 1);
  if (v.y) atomicAdd(&cnt[v.y - 1], 1);
  if (v.z) atomicAdd(&cnt[v.z - 1], 1);
  if (v.w) atomicAdd(&cnt[v.w - 1], 1);
}

// ---- compacted matching path ----
__global__ __launch_bounds__(256) void k_compact(const int* __restrict__ cnt,
                                                 int* __restrict__ roots,
                                                 int* __restrict__ cntD,
                                                 int* __restrict__ dense_of,
                                                 Scalars* sc) {
  int p = blockIdx.x * 256 + threadIdx.x;
  int c = cnt[p];
  bool has = c > 0;
  unsigned long long m = __ballot(has);
  int lane = threadIdx.x & 63;
  if (has) {
    int leader = __ffsll((unsigned long long)m) - 1;
    int prefix = __popcll(m & ((1ULL << lane) - 1ULL));
    int base = 0;
    if (lane == leader) base = atomicAdd(&sc->n_comp, __popcll(m));
    base = __shfl(base, leader);
    int d = base + prefix;
    if (d < CAP) { roots[d] = p; cntD[d] = c; dense_of[p] = d; }
  }
}

__global__ __launch_bounds__(256) void k_interall(const int* __restrict__ lab,
                                                  const int* __restrict__ tgt,
                                                  const int* __restrict__ dense_of,
                                                  int* __restrict__ interD) {
  int g = blockIdx.x * 256 + threadIdx.x;
  int4 v = *(const int4*)(lab + ((size_t)g << 2));
  int4 t = *(const int4*)(tgt + ((size_t)g << 2));
  if (v.x && t.x) atomicAdd(&interD[(dense_of[v.x - 1] << 4) + t.x - 1], 1);
  if (v.y && t.y) atomicAdd(&interD[(dense_of[v.y - 1] << 4) + t.y - 1], 1);
  if (v.z && t.z) atomicAdd(&interD[(dense_of[v.z - 1] << 4) + t.z - 1], 1);
  if (v.w && t.w) atomicAdd(&interD[(dense_of[v.w - 1] << 4) + t.w - 1], 1);
}

// fused argmin + greedy-step: last-arriving block performs the scalar update
__global__ __launch_bounds__(256) void k_match(const int* __restrict__ roots,
                                               int* __restrict__ cntD,
                                               const int* __restrict__ interD,
                                               const int* __restrict__ dense_of,
                                               Scalars* sc, int t, int grid) {
  int d = blockIdx.x * 256 + threadIdx.x;
  int nc = sc->n_comp;
  if (nc > CAP) nc = CAP;
  unsigned long long key = ~0ULL;
  if (d < nc) {
    int c = cntD[d];
    if (c > 0) {
      float ctf = (float)sc->cnt_t[t];
      float loss = pair_loss((float)c, (float)interD[(d << 4) + t - 1], ctf);
      key = ((unsigned long long)__float_as_uint(loss) << 32) | (unsigned)roots[d];
    }
  }
  for (int o = 32; o > 0; o >>= 1) {
    unsigned long long k2 = __shfl_down(key, o);
    key = (k2 < key) ? k2 : key;
  }
  __shared__ unsigned long long wmin[4];
  int lane = threadIdx.x & 63, wid = threadIdx.x >> 6;
  if (!lane) wmin[wid] = key;
  __syncthreads();
  if (!threadIdx.x) {
    unsigned long long k2 = wmin[0];
    if (wmin[1] < k2) k2 = wmin[1];
    if (wmin[2] < k2) k2 = wmin[2];
    if (wmin[3] < k2) k2 = wmin[3];
    if (k2 != ~0ULL) atomicMin(&sc->best, k2);
    __threadfence();
    int a = atomicAdd(&sc->arrive, 1);
    if (a == grid - 1) {   // last block: do the greedy step
      unsigned long long bb = atomicMin(&sc->best, ~0ULL);  // atomic read
      bool present = sc->cnt_t[t] > 0;
      bool any = bb != ~0ULL;
      if (present && any) {
        sc->acc += (double)__uint_as_float((unsigned)(bb >> 32));
        int root = (int)(bb & 0xFFFFFFFFu);
        int dd = dense_of[root];
        cntD[dd] = -cntD[dd];  // mark used
        sc->matched += 1;
      } else if (present) {
        sc->un_tgt += 1;
      }
      sc->best = ~0ULL;
      sc->arrive = 0;
    }
  }
}

// ---- fallback matching path over full N domain (small ws) ----
__global__ __launch_bounds__(256) void k_npred(const int* __restrict__ cnt, Scalars* sc) {
  int g = blockIdx.x * 256 + threadIdx.x;
  int4 v = *(const int4*)(cnt + ((size_t)g << 2));
  int n = (v.x > 0) + (v.y > 0) + (v.z > 0) + (v.w > 0);
  for (int o = 32; o > 0; o >>= 1) n += __shfl_down(n, o);
  if (!(threadIdx.x & 63) && n) atomicAdd(&sc->n_comp, n);
}

__global__ __launch_bounds__(256) void k_interN(const int* __restrict__ lab,
                                                const int* __restrict__ tgt,
                                                int* __restrict__ inter, int t) {
  int g = blockIdx.x * 256 + threadIdx.x;
  int4 v = *(const int4*)(lab + ((size_t)g << 2));
  int4 tv = *(const int4*)(tgt + ((size_t)g << 2));
  if (v.x && tv.x == t) atomicAdd(&inter[v.x - 1], 1);
  if (v.y && tv.y == t) atomicAdd(&inter[v.y - 1], 1);
  if (v.z && tv.z == t) atomicAdd(&inter[v.z - 1], 1);
  if (v.w && tv.w == t) atomicAdd(&inter[v.w - 1], 1);
}

__global__ __launch_bounds__(256) void k_matchN(int* __restrict__ cnt,
                                                int* __restrict__ inter,
                                                Scalars* sc, int t, int grid) {
  int p = blockIdx.x * 256 + threadIdx.x;
  int c = cnt[p];
  int iv = inter[p];
  inter[p] = 0;
  unsigned long long key = ~0ULL;
  if (c > 0) {
    float loss = pair_loss((float)c, (float)iv, (float)sc->cnt_t[t]);
    key = ((unsigned long long)__float_as_uint(loss) << 32) | (unsigned)p;
  }
  for (int o = 32; o > 0; o >>= 1) {
    unsigned long long k2 = __shfl_down(key, o);
    key = (k2 < key) ? k2 : key;
  }
  __shared__ unsigned long long wmin[4];
  int lane = threadIdx.x & 63, wid = threadIdx.x >> 6;
  if (!lane) wmin[wid] = key;
  __syncthreads();
  if (!threadIdx.x) {
    unsigned long long k2 = wmin[0];
    if (wmin[1] < k2) k2 = wmin[1];
    if (wmin[2] < k2) k2 = wmin[2];
    if (wmin[3] < k2) k2 = wmin[3];
    if (k2 != ~0ULL) atomicMin(&sc->best, k2);
    __threadfence();
    int a = atomicAdd(&sc->arrive, 1);
    if (a == grid - 1) {
      unsigned long long bb = atomicMin(&sc->best, ~0ULL);
      bool present = sc->cnt_t[t] > 0;
      bool any = bb != ~0ULL;
      if (present && any) {
        sc->acc += (double)__uint_as_float((unsigned)(bb >> 32));
        int root = (int)(bb & 0xFFFFFFFFu);
        cnt[root] = -cnt[root];
        sc->matched += 1;
      } else if (present) {
        sc->un_tgt += 1;
      }
      sc->best = ~0ULL;
      sc->arrive = 0;
    }
  }
}

__global__ void k_final(const Scalars* sc, float* out) {
  double Nd = (double)NPIX;
  double res = sc->sums[0] / Nd
             + 1.0 - (2.0 * sc->sums[2] + 1.0) / (sc->sums[1] + sc->sums[3] + 1.0);
  double total = res + sc->acc
               + (double)(sc->n_comp - sc->matched) + (double)sc->un_tgt;
  out[0] = (float)total;
}

extern "C" void kernel_launch(void* const* d_in, const int* in_sizes, int n_in,
                              void* d_out, int out_size, void* d_ws, size_t ws_size,
                              hipStream_t stream) {
  (void)in_sizes; (void)n_in; (void)out_size;
  const float* pred = (const float*)d_in[0];
  const int* tgt = (const int*)d_in[1];
  float* out = (float*)d_out;

  char* w = (char*)d_ws;
  int* lab_a = (int*)w;  w += (size_t)NPIX * 4;
  int* lab_b = (int*)w;  w += (size_t)NPIX * 4;   // prop ping-pong, later dense_of / inter
  int* cnt   = (int*)w;  w += (size_t)NPIX * 4;
  double* part = (double*)w; w += (size_t)INIT_BLOCKS * NPART * 8;
  Scalars* sc = (Scalars*)w; w += 256;
  int* roots  = (int*)w;
  int* cntD   = roots + CAP;
  int* interD = cntD + CAP;
  size_t need_full = (size_t)(w - (char*)d_ws) + (size_t)CAP * 8 + (size_t)CAP * 64;
  bool use_compact = ws_size >= need_full;

  hipMemsetAsync(cnt, 0, (size_t)NPIX * 4, stream);
  k_init<<<INIT_BLOCKS, 256, 0, stream>>>(pred, tgt, lab_a, part);
  k_reduce<<<1, 256, 0, stream>>>(part, sc);

  for (int k = 0; k < CCL_ITERS / (2 * RR); ++k) {   // 4 iterations x 2 launches = 8
    k_prop_tile<<<PROP_BLOCKS, PROP_THREADS, 0, stream>>>(lab_a, lab_b);
    k_prop_tile<<<PROP_BLOCKS, PROP_THREADS, 0, stream>>>(lab_b, lab_a);
  }

  k_count<<<NPIX / 1024, 256, 0, stream>>>(lab_a, cnt);

  if (use_compact) {
    hipMemsetAsync(interD, 0, (size_t)CAP * 64, stream);
    k_compact<<<NPIX / 256, 256, 0, stream>>>(cnt, roots, cntD, lab_b, sc);
    k_interall<<<NPIX / 1024, 256, 0, stream>>>(lab_a, tgt, lab_b, interD);
    const int G = CAP / 256;
    for (int t = 1; t <= TMAX; ++t)
      k_match<<<G, 256, 0, stream>>>(roots, cntD, interD, lab_b, sc, t, G);
  } else {
    k_npred<<<NPIX / 1024, 256, 0, stream>>>(cnt, sc);
    hipMemsetAsync(lab_b, 0, (size_t)NPIX * 4, stream);
    for (int t = 1; t <= TMAX; ++t) {
      k_interN<<<NPIX / 1024, 256, 0, stream>>>(lab_a, tgt, lab_b, t);
      k_matchN<<<NPIX / 256, 256, 0, stream>>>(cnt, lab_b, sc, t, NPIX / 256);
    }
  }

  k_final<<<1, 1, 0, stream>>>(sc, out);
}

// Round 3
// 167.336 us; speedup vs baseline: 13.6566x; 5.4125x over previous
//
#include <hip/hip_runtime.h>
#include <math.h>

#define HH 512
#define WW 512
#define HWSZ (HH * WW)          // 262144
#define NB 4
#define NPIX (NB * HWSZ)        // 1048576
#define TMAX 16

#define CAP 131072              // dense component capacity (observed n_comp ~70k)
#define INIT_BLOCKS 1024        // NPIX/4/256
#define NPART 24                // padded partials row (21 used)
#define CBLK 256                // compaction blocks; each covers 4096 roots
#define SBLK 512                // scanmins blocks; each covers 256 dense comps

struct Scalars {
  double sums[4];               // bce, sum_p, sum_pt, sum_t
  int cnt_t[TMAX + 1];
  int n_comp;
};

__device__ __forceinline__ float pair_loss(float cp, float it, float ctf) {
  const float Nf = (float)NPIX;
  float bce = (Nf * 0.69314718f + cp * 0.62011451f - it) / Nf;  // SP0, SP1-SP0
  float sum_pt = 0.5f * ctf + 0.23105858f * it;                 // S1-0.5
  float sum_p = 0.5f * Nf + 0.23105858f * cp;
  float dice = 1.0f - (2.0f * sum_pt + 1.0f) / (sum_p + ctf + 1.0f);
  return bce + dice;            // always > 0 -> float bits order == value order
}

// ---- init: fg mask, union-find parents, base-loss partials, target hist ----
__global__ __launch_bounds__(256) void k_init(const float* __restrict__ pred,
                                              const int* __restrict__ tgt,
                                              int* __restrict__ P,
                                              double* __restrict__ part) {
  __shared__ int hist[TMAX + 1];
  __shared__ double red[4][4];
  int tid = threadIdx.x;
  if (tid <= TMAX) hist[tid] = 0;
  __syncthreads();

  int g = blockIdx.x * 256 + tid;
  int i = g << 2;
  int b = i >> 18;
  int hw = i & (HWSZ - 1);
  const float* pb = pred + ((size_t)(b << 1)) * HWSZ;
  float4 p0 = *(const float4*)(pb + hw);
  float4 p1 = *(const float4*)(pb + HWSZ + hw);
  int4 tv = *(const int4*)(tgt + i);
  int4 lv;
  float s0 = 0.f, s1 = 0.f, s2 = 0.f, s3 = 0.f;

#define ELEM(P0, P1, TV, IDX, LOUT)                              \
  {                                                              \
    bool fg = (P1) > (P0);                                       \
    float logit = fg ? (P1) : 0.0f;                              \
    float tb = ((TV) > 0) ? 1.0f : 0.0f;                         \
    float sp = fmaxf(logit, 0.0f) + log1pf(expf(-fabsf(logit))); \
    s0 += sp - logit * tb;                                       \
    float pr = 1.0f / (1.0f + expf(-logit));                     \
    s1 += pr; s2 += pr * tb; s3 += tb;                           \
    atomicAdd(&hist[TV], 1);                                     \
    LOUT = fg ? (IDX) : -1;                                      \
  }
  ELEM(p0.x, p1.x, tv.x, i + 0, lv.x)
  ELEM(p0.y, p1.y, tv.y, i + 1, lv.y)
  ELEM(p0.z, p1.z, tv.z, i + 2, lv.z)
  ELEM(p0.w, p1.w, tv.w, i + 3, lv.w)
#undef ELEM
  *(int4*)(P + i) = lv;

  for (int o = 32; o > 0; o >>= 1) {
    s0 += __shfl_down(s0, o);
    s1 += __shfl_down(s1, o);
    s2 += __shfl_down(s2, o);
    s3 += __shfl_down(s3, o);
  }
  int lane = tid & 63, wid = tid >> 6;
  if (!lane) { red[wid][0] = s0; red[wid][1] = s1; red[wid][2] = s2; red[wid][3] = s3; }
  __syncthreads();
  double* row = part + (size_t)blockIdx.x * NPART;
  if (tid <= TMAX) row[4 + tid] = (double)hist[tid];
  if (!tid) {
    row[0] = red[0][0] + red[1][0] + red[2][0] + red[3][0];
    row[1] = red[0][1] + red[1][1] + red[2][1] + red[3][1];
    row[2] = red[0][2] + red[1][2] + red[2][2] + red[3][2];
    row[3] = red[0][3] + red[1][3] + red[2][3] + red[3][3];
  }
}

__global__ __launch_bounds__(256) void k_reduce(const double* __restrict__ part,
                                                Scalars* sc) {
  double v[21];
#pragma unroll
  for (int j = 0; j < 21; ++j) v[j] = 0.0;
  for (int r = threadIdx.x; r < INIT_BLOCKS; r += 256) {
    const double* row = part + (size_t)r * NPART;
#pragma unroll
    for (int j = 0; j < 21; ++j) v[j] += row[j];
  }
#pragma unroll
  for (int o = 32; o > 0; o >>= 1) {
#pragma unroll
    for (int j = 0; j < 21; ++j) v[j] += __shfl_down(v[j], o);
  }
  __shared__ double red[4][21];
  int lane = threadIdx.x & 63, wid = threadIdx.x >> 6;
  if (!lane) {
#pragma unroll
    for (int j = 0; j < 21; ++j) red[wid][j] = v[j];
  }
  __syncthreads();
  if (!threadIdx.x) {
#pragma unroll
    for (int j = 0; j < 21; ++j) v[j] = red[0][j] + red[1][j] + red[2][j] + red[3][j];
    sc->sums[0] = v[0]; sc->sums[1] = v[1]; sc->sums[2] = v[2]; sc->sums[3] = v[3];
    for (int j = 0; j <= TMAX; ++j) sc->cnt_t[j] = (int)(v[4 + j] + 0.5);
    sc->n_comp = 0;
  }
}

// ---- lock-free union-find (max-root), Playne-Azimi style mirrored ----
__device__ __forceinline__ int findRoot(const int* __restrict__ P, int x) {
  int p = P[x];
  while (p != x) { x = p; p = P[x]; }
  return x;
}

__device__ void unite(int* P, int a, int b) {
  a = findRoot(P, a);
  b = findRoot(P, b);
  for (;;) {
    if (a == b) return;
    if (a > b) { int t = a; a = b; b = t; }     // a < b : link a -> b
    int old = atomicMax(&P[a], b);
    if (old == a) return;                        // a was root, now under b
    a = findRoot(P, old);                        // merge remaining chains
    b = findRoot(P, b);
  }
}

__global__ __launch_bounds__(256) void k_link(int* __restrict__ P) {
  int i = blockIdx.x * 256 + threadIdx.x;
  if (P[i] < 0) return;                          // background
  int hw = i & (HWSZ - 1);
  int h = hw >> 9;
  int w = hw & (WW - 1);
  if (w < WW - 1 && P[i + 1] >= 0)  unite(P, i, i + 1);
  if (h < HH - 1 && P[i + WW] >= 0) unite(P, i, i + WW);
}

// flatten to labels (root+1, bg=0) + per-root pixel counts
__global__ __launch_bounds__(256) void k_flatcnt(const int* __restrict__ P,
                                                 int* __restrict__ lab,
                                                 int* __restrict__ cnt) {
  int i = blockIdx.x * 256 + threadIdx.x;
  int p = P[i];
  if (p < 0) { lab[i] = 0; return; }
  int r = i;
  while (p != r) { r = p; p = P[r]; }
  lab[i] = r + 1;
  atomicAdd(&cnt[r], 1);
}

// ---- ordered compaction: counts -> exclusive scan -> scatter (dense ids in root order)
__global__ __launch_bounds__(256) void k_bcnt(const int* __restrict__ cnt,
                                              int* __restrict__ bcnt) {
  int base = (blockIdx.x * 256 + threadIdx.x) << 4;
  int c = 0;
#pragma unroll
  for (int k = 0; k < 4; ++k) {
    int4 v = *(const int4*)(cnt + base + (k << 2));
    c += (v.x > 0) + (v.y > 0) + (v.z > 0) + (v.w > 0);
  }
  for (int o = 32; o > 0; o >>= 1) c += __shfl_down(c, o);
  __shared__ int red[4];
  int lane = threadIdx.x & 63, wid = threadIdx.x >> 6;
  if (!lane) red[wid] = c;
  __syncthreads();
  if (!threadIdx.x) bcnt[blockIdx.x] = red[0] + red[1] + red[2] + red[3];
}

__global__ __launch_bounds__(256) void k_scanexc(int* __restrict__ bcnt, Scalars* sc) {
  int tid = threadIdx.x;
  int lane = tid & 63, wv = tid >> 6;
  int orig = bcnt[tid];
  int v = orig;
  for (int o = 1; o < 64; o <<= 1) {
    int u = __shfl_up(v, o);
    if (lane >= o) v += u;
  }
  __shared__ int wtot[4];
  if (lane == 63) wtot[wv] = v;
  __syncthreads();
  int add = 0;
  for (int w = 0; w < wv; ++w) add += wtot[w];
  v += add;
  bcnt[tid] = v - orig;             // exclusive
  if (tid == 255) sc->n_comp = v;   // total
}

// scatter: cntD[dense]=count ; cnt[root] <- dense id (in-place dense_of)
__global__ __launch_bounds__(256) void k_scatter(int* __restrict__ cnt,
                                                 const int* __restrict__ bcnt,
                                                 int* __restrict__ cntD) {
  int tid = threadIdx.x;
  int base = (blockIdx.x * 256 + tid) << 4;
  int val[16];
  int cme = 0;
#pragma unroll
  for (int k = 0; k < 4; ++k) {
    int4 v = *(const int4*)(cnt + base + (k << 2));
    val[(k << 2) + 0] = v.x; val[(k << 2) + 1] = v.y;
    val[(k << 2) + 2] = v.z; val[(k << 2) + 3] = v.w;
    cme += (v.x > 0) + (v.y > 0) + (v.z > 0) + (v.w > 0);
  }
  int lane = tid & 63, wv = tid >> 6;
  int v = cme;
  for (int o = 1; o < 64; o <<= 1) {
    int u = __shfl_up(v, o);
    if (lane >= o) v += u;
  }
  __shared__ int wtot[4];
  if (lane == 63) wtot[wv] = v;
  __syncthreads();
  int add = 0;
  for (int w = 0; w < wv; ++w) add += wtot[w];
  int d = bcnt[blockIdx.x] + v + add - cme;     // exclusive prefix
#pragma unroll
  for (int k = 0; k < 16; ++k) {
    int c = val[k];
    if (c > 0) {
      if (d < CAP) cntD[d] = c;
      cnt[base + k] = d;
      ++d;
    }
  }
}

// confusion counts for ALL t in one pixel pass
__global__ __launch_bounds__(256) void k_interall(const int* __restrict__ lab,
                                                  const int* __restrict__ tgt,
                                                  const int* __restrict__ dense_of,
                                                  int* __restrict__ interD) {
  int g = blockIdx.x * 256 + threadIdx.x;
  int4 v = *(const int4*)(lab + ((size_t)g << 2));
  int4 t = *(const int4*)(tgt + ((size_t)g << 2));
#define DO(V, T)                                                   \
  if ((V) && (T)) {                                                \
    int dD = dense_of[(V) - 1];                                    \
    if ((unsigned)dD < CAP) atomicAdd(&interD[(dD << 4) + (T) - 1], 1); \
  }
  DO(v.x, t.x) DO(v.y, t.y) DO(v.z, t.z) DO(v.w, t.w)
#undef DO
}

// per-(block,t) min keys (loss_bits<<32 | dense); dense order == root order
__global__ __launch_bounds__(256) void k_scanmins(const Scalars* __restrict__ sc,
                                                  const int* __restrict__ cntD,
                                                  const int* __restrict__ interD,
                                                  unsigned long long* __restrict__ bm) {
  int tid = threadIdx.x;
  int d = blockIdx.x * 256 + tid;
  int c = cntD[d];
  int itv[16];
  if (c > 0) {
#pragma unroll
    for (int k = 0; k < 4; ++k) {
      int4 r = *(const int4*)(interD + ((size_t)d << 4) + (k << 2));
      itv[(k << 2) + 0] = r.x; itv[(k << 2) + 1] = r.y;
      itv[(k << 2) + 2] = r.z; itv[(k << 2) + 3] = r.w;
    }
  }
  __shared__ unsigned long long wmin[4][16];
  float cp = (float)c;
  int lane = tid & 63, wv = tid >> 6;
#pragma unroll
  for (int t = 0; t < 16; ++t) {
    unsigned long long key = ~0ULL;
    if (c > 0) {
      float loss = pair_loss(cp, (float)itv[t], (float)sc->cnt_t[t + 1]);
      key = ((unsigned long long)__float_as_uint(loss) << 32) | (unsigned)d;
    }
    for (int o = 32; o > 0; o >>= 1) {
      unsigned long long kk = __shfl_down(key, o);
      if (kk < key) key = kk;
    }
    if (!lane) wmin[wv][t] = key;
  }
  __syncthreads();
  if (tid < 16) {
    unsigned long long m = wmin[0][tid];
    if (wmin[1][tid] < m) m = wmin[1][tid];
    if (wmin[2][tid] < m) m = wmin[2][tid];
    if (wmin[3][tid] < m) m = wmin[3][tid];
    bm[(size_t)tid * SBLK + blockIdx.x] = m;
  }
}

// single-block sequential greedy over per-block mins; re-scan a block only
// when its min turns out to be an already-used comp.
__global__ __launch_bounds__(256) void k_greedy(const Scalars* __restrict__ sc,
                                                const int* __restrict__ cntD,
                                                const int* __restrict__ interD,
                                                unsigned long long* __restrict__ bm,
                                                float* __restrict__ out) {
  __shared__ int s_used[16];
  __shared__ int s_nused;
  __shared__ unsigned long long s_m;
  __shared__ int s_state;                 // 0=accept 1=retry 2=none-avail
  __shared__ unsigned long long wmin[4];
  int tid = threadIdx.x;
  int lane = tid & 63, wv = tid >> 6;
  if (!tid) s_nused = 0;
  __syncthreads();

  double acc = 0.0;
  int matched = 0, un = 0;
  int n_comp = sc->n_comp;

  for (int t = 1; t <= TMAX; ++t) {
    int ct = sc->cnt_t[t];
    if (ct == 0) continue;
    for (int iter = 0; iter < 64; ++iter) {
      const unsigned long long* row = bm + (size_t)(t - 1) * SBLK;
      unsigned long long k1 = row[tid];
      unsigned long long k2 = row[tid + 256];
      unsigned long long key = (k2 < k1) ? k2 : k1;
      for (int o = 32; o > 0; o >>= 1) {
        unsigned long long kk = __shfl_down(key, o);
        if (kk < key) key = kk;
      }
      if (!lane) wmin[wv] = key;
      __syncthreads();
      if (!tid) {
        unsigned long long m = wmin[0];
        if (wmin[1] < m) m = wmin[1];
        if (wmin[2] < m) m = wmin[2];
        if (wmin[3] < m) m = wmin[3];
        s_m = m;
        int st = 0;
        if (m == ~0ULL) st = 2;
        else {
          int dd = (int)(m & 0xFFFFFFFFu);
          for (int u = 0; u < s_nused; ++u)
            if (s_used[u] == dd) { st = 1; break; }
        }
        s_state = st;
      }
      __syncthreads();
      int st = s_state;
      unsigned long long m = s_m;
      if (st == 0) {
        acc += (double)__uint_as_float((unsigned)(m >> 32));
        matched += 1;
        if (!tid) { s_used[s_nused] = (int)(m & 0xFFFFFFFFu); s_nused++; }
        break;
      } else if (st == 2) {
        un += 1;
        break;
      } else {
        // rebuild block b's min for this t, excluding used comps
        int dd = (int)(m & 0xFFFFFFFFu);
        int b = dd >> 8;
        int d2 = (b << 8) + tid;
        unsigned long long nk = ~0ULL;
        int c = cntD[d2];
        if (c > 0) {
          bool ex = false;
          for (int u = 0; u < s_nused; ++u)
            if (s_used[u] == d2) { ex = true; break; }
          if (!ex) {
            float loss = pair_loss((float)c, (float)interD[((size_t)d2 << 4) + (t - 1)], (float)ct);
            nk = ((unsigned long long)__float_as_uint(loss) << 32) | (unsigned)d2;
          }
        }
        for (int o = 32; o > 0; o >>= 1) {
          unsigned long long kk = __shfl_down(nk, o);
          if (kk < nk) nk = kk;
        }
        if (!lane) wmin[wv] = nk;
        __syncthreads();
        if (!tid) {
          unsigned long long mm = wmin[0];
          if (wmin[1] < mm) mm = wmin[1];
          if (wmin[2] < mm) mm = wmin[2];
          if (wmin[3] < mm) mm = wmin[3];
          bm[(size_t)(t - 1) * SBLK + b] = mm;
        }
        __syncthreads();
      }
    }
    __syncthreads();   // make s_used/s_nused updates visible before next t
  }

  if (!tid) {
    double Nd = (double)NPIX;
    double res = sc->sums[0] / Nd
               + 1.0 - (2.0 * sc->sums[2] + 1.0) / (sc->sums[1] + sc->sums[3] + 1.0);
    out[0] = (float)(res + acc + (double)(n_comp - matched) + (double)un);
  }
}

extern "C" void kernel_launch(void* const* d_in, const int* in_sizes, int n_in,
                              void* d_out, int out_size, void* d_ws, size_t ws_size,
                              hipStream_t stream) {
  (void)in_sizes; (void)n_in; (void)out_size; (void)ws_size;
  const float* pred = (const float*)d_in[0];
  const int* tgt = (const int*)d_in[1];
  float* out = (float*)d_out;

  char* w = (char*)d_ws;
  int* P     = (int*)w;            w += (size_t)NPIX * 4;     // union-find parents
  int* lab   = (int*)w;            w += (size_t)NPIX * 4;     // root+1 labels
  int* cnt   = (int*)w;            w += (size_t)NPIX * 4;     // counts -> dense_of
  double* part = (double*)w;       w += (size_t)INIT_BLOCKS * NPART * 8;
  Scalars* sc = (Scalars*)w;       w += 256;
  int* bcnt  = (int*)w;            w += 1024;
  int* cntD  = (int*)w;            w += (size_t)CAP * 4;
  unsigned long long* bm = (unsigned long long*)w; w += (size_t)16 * SBLK * 8;
  int* interD = (int*)w;           // CAP * 16 * 4 = 8 MB

  hipMemsetAsync(cnt, 0, (size_t)NPIX * 4, stream);
  hipMemsetAsync(cntD, 0, (size_t)CAP * 4, stream);
  hipMemsetAsync(interD, 0, (size_t)CAP * 64, stream);

  k_init<<<INIT_BLOCKS, 256, 0, stream>>>(pred, tgt, P, part);
  k_reduce<<<1, 256, 0, stream>>>(part, sc);
  k_link<<<NPIX / 256, 256, 0, stream>>>(P);
  k_flatcnt<<<NPIX / 256, 256, 0, stream>>>(P, lab, cnt);
  k_bcnt<<<CBLK, 256, 0, stream>>>(cnt, bcnt);
  k_scanexc<<<1, 256, 0, stream>>>(bcnt, sc);
  k_scatter<<<CBLK, 256, 0, stream>>>(cnt, bcnt, cntD);
  k_interall<<<NPIX / 1024, 256, 0, stream>>>(lab, tgt, cnt, interD);
  k_scanmins<<<SBLK, 256, 0, stream>>>(sc, cntD, interD, bm);
  k_greedy<<<1, 256, 0, stream>>>(sc, cntD, interD, bm, out);
}

// Round 4
// 157.943 us; speedup vs baseline: 14.4688x; 1.0595x over previous
//
#include <hip/hip_runtime.h>
#include <math.h>

#define HH 512
#define WW 512
#define HWSZ (HH * WW)          // 262144
#define NB 4
#define NPIX (NB * HWSZ)        // 1048576
#define TMAX 16

#define CAP 131072              // dense component capacity (observed n_comp ~70k)
#define INIT_BLOCKS 1024        // NPIX/4/256
#define NPART 24                // padded partials row (21 used)
#define CBLK 256                // compaction blocks; each covers 4096 roots
#define SBLK 512                // scanmins blocks; each covers 256 dense comps

struct Scalars {
  double sums[4];               // bce, sum_p, sum_pt, sum_t
  int cnt_t[TMAX + 1];
  int n_comp;
};

__device__ __forceinline__ float pair_loss(float cp, float it, float ctf) {
  const float Nf = (float)NPIX;
  float bce = (Nf * 0.69314718f + cp * 0.62011451f - it) / Nf;  // SP0, SP1-SP0
  float sum_pt = 0.5f * ctf + 0.23105858f * it;                 // S1-0.5
  float sum_p = 0.5f * Nf + 0.23105858f * cp;
  float dice = 1.0f - (2.0f * sum_pt + 1.0f) / (sum_p + ctf + 1.0f);
  return bce + dice;            // always > 0 -> float bits order == value order
}

// ---- init: fg mask, union-find parents, zero cnt, partials, target hist ----
__global__ __launch_bounds__(256) void k_init(const float* __restrict__ pred,
                                              const int* __restrict__ tgt,
                                              int* __restrict__ P,
                                              int* __restrict__ cnt,
                                              double* __restrict__ part) {
  __shared__ int hist[TMAX + 1];
  __shared__ double red[4][4];
  int tid = threadIdx.x;
  if (tid <= TMAX) hist[tid] = 0;
  __syncthreads();

  int g = blockIdx.x * 256 + tid;
  int i = g << 2;
  int b = i >> 18;
  int hw = i & (HWSZ - 1);
  const float* pb = pred + ((size_t)(b << 1)) * HWSZ;
  float4 p0 = *(const float4*)(pb + hw);
  float4 p1 = *(const float4*)(pb + HWSZ + hw);
  int4 tv = *(const int4*)(tgt + i);
  int4 lv;
  float s0 = 0.f, s1 = 0.f, s2 = 0.f, s3 = 0.f;

#define ELEM(P0, P1, TV, IDX, LOUT)                              \
  {                                                              \
    bool fg = (P1) > (P0);                                       \
    float logit = fg ? (P1) : 0.0f;                              \
    float tb = ((TV) > 0) ? 1.0f : 0.0f;                         \
    float sp = fmaxf(logit, 0.0f) + log1pf(expf(-fabsf(logit))); \
    s0 += sp - logit * tb;                                       \
    float pr = 1.0f / (1.0f + expf(-logit));                     \
    s1 += pr; s2 += pr * tb; s3 += tb;                           \
    atomicAdd(&hist[TV], 1);                                     \
    LOUT = fg ? (IDX) : -1;                                      \
  }
  ELEM(p0.x, p1.x, tv.x, i + 0, lv.x)
  ELEM(p0.y, p1.y, tv.y, i + 1, lv.y)
  ELEM(p0.z, p1.z, tv.z, i + 2, lv.z)
  ELEM(p0.w, p1.w, tv.w, i + 3, lv.w)
#undef ELEM
  *(int4*)(P + i) = lv;
  *(int4*)(cnt + i) = make_int4(0, 0, 0, 0);   // fused zeroing (replaces memset)

  for (int o = 32; o > 0; o >>= 1) {
    s0 += __shfl_down(s0, o);
    s1 += __shfl_down(s1, o);
    s2 += __shfl_down(s2, o);
    s3 += __shfl_down(s3, o);
  }
  int lane = tid & 63, wid = tid >> 6;
  if (!lane) { red[wid][0] = s0; red[wid][1] = s1; red[wid][2] = s2; red[wid][3] = s3; }
  __syncthreads();
  double* row = part + (size_t)blockIdx.x * NPART;
  if (tid <= TMAX) row[4 + tid] = (double)hist[tid];
  if (!tid) {
    row[0] = red[0][0] + red[1][0] + red[2][0] + red[3][0];
    row[1] = red[0][1] + red[1][1] + red[2][1] + red[3][1];
    row[2] = red[0][2] + red[1][2] + red[2][2] + red[3][2];
    row[3] = red[0][3] + red[1][3] + red[2][3] + red[3][3];
  }
}

__global__ __launch_bounds__(256) void k_reduce(const double* __restrict__ part,
                                                Scalars* sc) {
  double v[21];
#pragma unroll
  for (int j = 0; j < 21; ++j) v[j] = 0.0;
  for (int r = threadIdx.x; r < INIT_BLOCKS; r += 256) {
    const double* row = part + (size_t)r * NPART;
#pragma unroll
    for (int j = 0; j < 21; ++j) v[j] += row[j];
  }
#pragma unroll
  for (int o = 32; o > 0; o >>= 1) {
#pragma unroll
    for (int j = 0; j < 21; ++j) v[j] += __shfl_down(v[j], o);
  }
  __shared__ double red[4][21];
  int lane = threadIdx.x & 63, wid = threadIdx.x >> 6;
  if (!lane) {
#pragma unroll
    for (int j = 0; j < 21; ++j) red[wid][j] = v[j];
  }
  __syncthreads();
  if (!threadIdx.x) {
#pragma unroll
    for (int j = 0; j < 21; ++j) v[j] = red[0][j] + red[1][j] + red[2][j] + red[3][j];
    sc->sums[0] = v[0]; sc->sums[1] = v[1]; sc->sums[2] = v[2]; sc->sums[3] = v[3];
    for (int j = 0; j <= TMAX; ++j) sc->cnt_t[j] = (int)(v[4 + j] + 0.5);
    sc->n_comp = 0;
  }
}

// ---- lock-free union-find (max-root), Playne-Azimi style mirrored ----
__device__ __forceinline__ int findRoot(const int* __restrict__ P, int x) {
  int p = P[x];
  while (p != x) { x = p; p = P[x]; }
  return x;
}

__device__ void unite(int* P, int a, int b) {
  a = findRoot(P, a);
  b = findRoot(P, b);
  for (;;) {
    if (a == b) return;
    if (a > b) { int t = a; a = b; b = t; }     // a < b : link a -> b
    int old = atomicMax(&P[a], b);
    if (old == a) return;                        // a was root, now under b
    a = findRoot(P, old);                        // merge remaining chains
    b = findRoot(P, b);
  }
}

__global__ __launch_bounds__(256) void k_link(int* __restrict__ P) {
  int i = blockIdx.x * 256 + threadIdx.x;
  if (P[i] < 0) return;                          // background
  int hw = i & (HWSZ - 1);
  int h = hw >> 9;
  int w = hw & (WW - 1);
  if (w < WW - 1 && P[i + 1] >= 0)  unite(P, i, i + 1);
  if (h < HH - 1 && P[i + WW] >= 0) unite(P, i, i + WW);
}

// flatten to labels (root+1, bg=0) + per-root pixel counts + zero interD
__global__ __launch_bounds__(256) void k_flatcnt(const int* __restrict__ P,
                                                 int* __restrict__ lab,
                                                 int* __restrict__ cnt,
                                                 int* __restrict__ interD) {
  int i = blockIdx.x * 256 + threadIdx.x;
  *(int2*)(interD + ((size_t)i << 1)) = make_int2(0, 0);  // fused zeroing (2M ints)
  int p = P[i];
  if (p < 0) { lab[i] = 0; return; }
  int r = i;
  while (p != r) { r = p; p = P[r]; }
  lab[i] = r + 1;
  atomicAdd(&cnt[r], 1);
}

// ---- ordered compaction: counts -> exclusive scan -> scatter (dense ids in root order)
__global__ __launch_bounds__(256) void k_bcnt(const int* __restrict__ cnt,
                                              int* __restrict__ bcnt) {
  int base = (blockIdx.x * 256 + threadIdx.x) << 4;
  int c = 0;
#pragma unroll
  for (int k = 0; k < 4; ++k) {
    int4 v = *(const int4*)(cnt + base + (k << 2));
    c += (v.x > 0) + (v.y > 0) + (v.z > 0) + (v.w > 0);
  }
  for (int o = 32; o > 0; o >>= 1) c += __shfl_down(c, o);
  __shared__ int red[4];
  int lane = threadIdx.x & 63, wid = threadIdx.x >> 6;
  if (!lane) red[wid] = c;
  __syncthreads();
  if (!threadIdx.x) bcnt[blockIdx.x] = red[0] + red[1] + red[2] + red[3];
}

__global__ __launch_bounds__(256) void k_scanexc(int* __restrict__ bcnt, Scalars* sc) {
  int tid = threadIdx.x;
  int lane = tid & 63, wv = tid >> 6;
  int orig = bcnt[tid];
  int v = orig;
  for (int o = 1; o < 64; o <<= 1) {
    int u = __shfl_up(v, o);
    if (lane >= o) v += u;
  }
  __shared__ int wtot[4];
  if (lane == 63) wtot[wv] = v;
  __syncthreads();
  int add = 0;
  for (int w = 0; w < wv; ++w) add += wtot[w];
  v += add;
  bcnt[tid] = v - orig;             // exclusive
  if (tid == 255) sc->n_comp = v;   // total
}

// scatter: cntD[dense]=count ; cnt[root] <- dense id (in-place dense_of)
__global__ __launch_bounds__(256) void k_scatter(int* __restrict__ cnt,
                                                 const int* __restrict__ bcnt,
                                                 int* __restrict__ cntD) {
  int tid = threadIdx.x;
  int base = (blockIdx.x * 256 + tid) << 4;
  int val[16];
  int cme = 0;
#pragma unroll
  for (int k = 0; k < 4; ++k) {
    int4 v = *(const int4*)(cnt + base + (k << 2));
    val[(k << 2) + 0] = v.x; val[(k << 2) + 1] = v.y;
    val[(k << 2) + 2] = v.z; val[(k << 2) + 3] = v.w;
    cme += (v.x > 0) + (v.y > 0) + (v.z > 0) + (v.w > 0);
  }
  int lane = tid & 63, wv = tid >> 6;
  int v = cme;
  for (int o = 1; o < 64; o <<= 1) {
    int u = __shfl_up(v, o);
    if (lane >= o) v += u;
  }
  __shared__ int wtot[4];
  if (lane == 63) wtot[wv] = v;
  __syncthreads();
  int add = 0;
  for (int w = 0; w < wv; ++w) add += wtot[w];
  int d = bcnt[blockIdx.x] + v + add - cme;     // exclusive prefix
#pragma unroll
  for (int k = 0; k < 16; ++k) {
    int c = val[k];
    if (c > 0) {
      if (d < CAP) cntD[d] = c;
      cnt[base + k] = d;
      ++d;
    }
  }
}

// confusion counts for ALL t in one pixel pass
__global__ __launch_bounds__(256) void k_interall(const int* __restrict__ lab,
                                                  const int* __restrict__ tgt,
                                                  const int* __restrict__ dense_of,
                                                  int* __restrict__ interD) {
  int g = blockIdx.x * 256 + threadIdx.x;
  int4 v = *(const int4*)(lab + ((size_t)g << 2));
  int4 t = *(const int4*)(tgt + ((size_t)g << 2));
#define DO(V, T)                                                   \
  if ((V) && (T)) {                                                \
    int dD = dense_of[(V) - 1];                                    \
    if ((unsigned)dD < CAP) atomicAdd(&interD[(dD << 4) + (T) - 1], 1); \
  }
  DO(v.x, t.x) DO(v.y, t.y) DO(v.z, t.z) DO(v.w, t.w)
#undef DO
}

// per-(block,t) min keys (loss_bits<<32 | dense); dense order == root order
__global__ __launch_bounds__(256) void k_scanmins(const Scalars* __restrict__ sc,
                                                  const int* __restrict__ cntD,
                                                  const int* __restrict__ interD,
                                                  unsigned long long* __restrict__ bm) {
  int tid = threadIdx.x;
  int d = blockIdx.x * 256 + tid;
  int n_comp = sc->n_comp;
  int c = (d < n_comp) ? cntD[d] : 0;
  int itv[16];
  if (c > 0) {
#pragma unroll
    for (int k = 0; k < 4; ++k) {
      int4 r = *(const int4*)(interD + ((size_t)d << 4) + (k << 2));
      itv[(k << 2) + 0] = r.x; itv[(k << 2) + 1] = r.y;
      itv[(k << 2) + 2] = r.z; itv[(k << 2) + 3] = r.w;
    }
  }
  __shared__ unsigned long long wmin[4][16];
  float cp = (float)c;
  int lane = tid & 63, wv = tid >> 6;
#pragma unroll
  for (int t = 0; t < 16; ++t) {
    unsigned long long key = ~0ULL;
    if (c > 0) {
      float loss = pair_loss(cp, (float)itv[t], (float)sc->cnt_t[t + 1]);
      key = ((unsigned long long)__float_as_uint(loss) << 32) | (unsigned)d;
    }
    for (int o = 32; o > 0; o >>= 1) {
      unsigned long long kk = __shfl_down(key, o);
      if (kk < key) key = kk;
    }
    if (!lane) wmin[wv][t] = key;
  }
  __syncthreads();
  if (tid < 16) {
    unsigned long long m = wmin[0][tid];
    if (wmin[1][tid] < m) m = wmin[1][tid];
    if (wmin[2][tid] < m) m = wmin[2][tid];
    if (wmin[3][tid] < m) m = wmin[3][tid];
    bm[(size_t)tid * SBLK + blockIdx.x] = m;
  }
}

// single-block sequential greedy over per-block mins; re-scan a block only
// when its min turns out to be an already-used comp.
__global__ __launch_bounds__(256) void k_greedy(const Scalars* __restrict__ sc,
                                                const int* __restrict__ cntD,
                                                const int* __restrict__ interD,
                                                unsigned long long* __restrict__ bm,
                                                float* __restrict__ out) {
  __shared__ int s_used[16];
  __shared__ int s_nused;
  __shared__ unsigned long long s_m;
  __shared__ int s_state;                 // 0=accept 1=retry 2=none-avail
  __shared__ unsigned long long wmin[4];
  int tid = threadIdx.x;
  int lane = tid & 63, wv = tid >> 6;
  if (!tid) s_nused = 0;
  __syncthreads();

  double acc = 0.0;
  int matched = 0, un = 0;
  int n_comp = sc->n_comp;

  for (int t = 1; t <= TMAX; ++t) {
    int ct = sc->cnt_t[t];
    if (ct == 0) continue;
    for (int iter = 0; iter < 64; ++iter) {
      const unsigned long long* row = bm + (size_t)(t - 1) * SBLK;
      unsigned long long k1 = row[tid];
      unsigned long long k2 = row[tid + 256];
      unsigned long long key = (k2 < k1) ? k2 : k1;
      for (int o = 32; o > 0; o >>= 1) {
        unsigned long long kk = __shfl_down(key, o);
        if (kk < key) key = kk;
      }
      if (!lane) wmin[wv] = key;
      __syncthreads();
      if (!tid) {
        unsigned long long m = wmin[0];
        if (wmin[1] < m) m = wmin[1];
        if (wmin[2] < m) m = wmin[2];
        if (wmin[3] < m) m = wmin[3];
        s_m = m;
        int st = 0;
        if (m == ~0ULL) st = 2;
        else {
          int dd = (int)(m & 0xFFFFFFFFu);
          for (int u = 0; u < s_nused; ++u)
            if (s_used[u] == dd) { st = 1; break; }
        }
        s_state = st;
      }
      __syncthreads();
      int st = s_state;
      unsigned long long m = s_m;
      if (st == 0) {
        acc += (double)__uint_as_float((unsigned)(m >> 32));
        matched += 1;
        if (!tid) { s_used[s_nused] = (int)(m & 0xFFFFFFFFu); s_nused++; }
        break;
      } else if (st == 2) {
        un += 1;
        break;
      } else {
        // rebuild block b's min for this t, excluding used comps
        int dd = (int)(m & 0xFFFFFFFFu);
        int b = dd >> 8;
        int d2 = (b << 8) + tid;
        unsigned long long nk = ~0ULL;
        int c = (d2 < n_comp) ? cntD[d2] : 0;
        if (c > 0) {
          bool ex = false;
          for (int u = 0; u < s_nused; ++u)
            if (s_used[u] == d2) { ex = true; break; }
          if (!ex) {
            float loss = pair_loss((float)c, (float)interD[((size_t)d2 << 4) + (t - 1)], (float)ct);
            nk = ((unsigned long long)__float_as_uint(loss) << 32) | (unsigned)d2;
          }
        }
        for (int o = 32; o > 0; o >>= 1) {
          unsigned long long kk = __shfl_down(nk, o);
          if (kk < nk) nk = kk;
        }
        if (!lane) wmin[wv] = nk;
        __syncthreads();
        if (!tid) {
          unsigned long long mm = wmin[0];
          if (wmin[1] < mm) mm = wmin[1];
          if (wmin[2] < mm) mm = wmin[2];
          if (wmin[3] < mm) mm = wmin[3];
          bm[(size_t)(t - 1) * SBLK + b] = mm;
        }
        __syncthreads();
      }
    }
    __syncthreads();   // make s_used/s_nused updates visible before next t
  }

  if (!tid) {
    double Nd = (double)NPIX;
    double res = sc->sums[0] / Nd
               + 1.0 - (2.0 * sc->sums[2] + 1.0) / (sc->sums[1] + sc->sums[3] + 1.0);
    out[0] = (float)(res + acc + (double)(n_comp - matched) + (double)un);
  }
}

extern "C" void kernel_launch(void* const* d_in, const int* in_sizes, int n_in,
                              void* d_out, int out_size, void* d_ws, size_t ws_size,
                              hipStream_t stream) {
  (void)in_sizes; (void)n_in; (void)out_size; (void)ws_size;
  const float* pred = (const float*)d_in[0];
  const int* tgt = (const int*)d_in[1];
  float* out = (float*)d_out;

  char* w = (char*)d_ws;
  int* P     = (int*)w;            w += (size_t)NPIX * 4;     // union-find parents
  int* lab   = (int*)w;            w += (size_t)NPIX * 4;     // root+1 labels
  int* cnt   = (int*)w;            w += (size_t)NPIX * 4;     // counts -> dense_of
  double* part = (double*)w;       w += (size_t)INIT_BLOCKS * NPART * 8;
  Scalars* sc = (Scalars*)w;       w += 256;
  int* bcnt  = (int*)w;            w += 1024;
  int* cntD  = (int*)w;            w += (size_t)CAP * 4;
  unsigned long long* bm = (unsigned long long*)w; w += (size_t)16 * SBLK * 8;
  int* interD = (int*)w;           // CAP * 16 * 4 = 8 MB

  k_init<<<INIT_BLOCKS, 256, 0, stream>>>(pred, tgt, P, cnt, part);
  k_reduce<<<1, 256, 0, stream>>>(part, sc);
  k_link<<<NPIX / 256, 256, 0, stream>>>(P);
  k_flatcnt<<<NPIX / 256, 256, 0, stream>>>(P, lab, cnt, interD);
  k_bcnt<<<CBLK, 256, 0, stream>>>(cnt, bcnt);
  k_scanexc<<<1, 256, 0, stream>>>(bcnt, sc);
  k_scatter<<<CBLK, 256, 0, stream>>>(cnt, bcnt, cntD);
  k_interall<<<NPIX / 1024, 256, 0, stream>>>(lab, tgt, cnt, interD);
  k_scanmins<<<SBLK, 256, 0, stream>>>(sc, cntD, interD, bm);
  k_greedy<<<1, 256, 0, stream>>>(sc, cntD, interD, bm, out);
}